// Round 1
// baseline (583.399 us; speedup 1.0000x reference)
//
#include <hip/hip_runtime.h>
#include <hip/hip_bf16.h>
#include <cstdint>

#define B_ 256
#define T_ 600
#define D_ 256

__device__ __forceinline__ float fast_sigmoid(float x) {
    return __fdividef(1.0f, 1.0f + __expf(-x));
}
__device__ __forceinline__ float fast_tanh(float x) {
    return 1.0f - __fdividef(2.0f, __expf(2.0f * x) + 1.0f);
}

// ---------------------------------------------------------------------------
// init_concat: fill static parts of X_gru [B,640] and X_rnn [B,832]
// X_gru: [0:256)=ctx_in, [384:640)=spk   (prenet fills [256:384))
// X_rnn: [512:768)=spk, [768:832)=noise  (ctx/attn_hidden filled later)
// ---------------------------------------------------------------------------
__global__ __launch_bounds__(256) void init_concat(
    const float* __restrict__ ctx_in, const float* __restrict__ spk,
    const float* __restrict__ noise,
    float* __restrict__ Xgru, float* __restrict__ Xrnn)
{
    int b = blockIdx.x, t = threadIdx.x;
    float s = spk[b * 256 + t];
    Xgru[b * 640 + t] = ctx_in[b * 256 + t];
    Xgru[b * 640 + 384 + t] = s;
    Xrnn[b * 832 + 512 + t] = s;
    if (t < 64) Xrnn[b * 832 + 768 + t] = noise[b * 64 + t];
}

// ---------------------------------------------------------------------------
// prenet: relu(relu([prenet_in,noise] @ fc1^T + b1) @ fc2^T + b2) -> Xgru[:,256:384]
// ---------------------------------------------------------------------------
__global__ __launch_bounds__(256) void prenet_kernel(
    const float* __restrict__ pre_in, const float* __restrict__ noise,
    const float* __restrict__ w1, const float* __restrict__ b1,
    const float* __restrict__ w2, const float* __restrict__ b2,
    float* __restrict__ Xgru)
{
    __shared__ float xin[144];
    __shared__ float p1[256];
    int b = blockIdx.x, t = threadIdx.x;
    if (t < 80) xin[t] = pre_in[b * 80 + t];
    else if (t < 144) xin[t] = noise[b * 64 + (t - 80)];
    __syncthreads();
    float acc = b1[t];
    const float4* w = (const float4*)(w1 + t * 144);
    const float4* xi = (const float4*)xin;
#pragma unroll 9
    for (int k = 0; k < 36; ++k) {
        float4 wv = w[k]; float4 xv = xi[k];
        acc += wv.x * xv.x + wv.y * xv.y + wv.z * xv.z + wv.w * xv.w;
    }
    p1[t] = fmaxf(acc, 0.f);
    __syncthreads();
    if (t < 128) {
        float a2 = b2[t];
        const float4* w2v = (const float4*)(w2 + t * 256);
        const float4* pv = (const float4*)p1;
#pragma unroll 8
        for (int k = 0; k < 64; ++k) {
            float4 wv = w2v[k]; float4 xv = pv[k];
            a2 += wv.x * xv.x + wv.y * xv.y + wv.z * xv.z + wv.w * xv.w;
        }
        Xgru[b * 640 + 256 + t] = fmaxf(a2, 0.f);
    }
}

// ---------------------------------------------------------------------------
// gemm_dual: C[M,N] = A1[M,K1] @ B1[N,K1]^T + A2[M,K2] @ B2[N,K2]^T (+bias[n])
// 64x64 tile, 256 threads, 4x4 per thread. M,N multiples of 64; K1,K2 of 16.
// ---------------------------------------------------------------------------
__global__ __launch_bounds__(256) void gemm_dual(
    const float* __restrict__ A1, int K1, const float* __restrict__ B1,
    const float* __restrict__ A2, int K2, const float* __restrict__ B2,
    const float* __restrict__ bias, float* __restrict__ C, int N)
{
    __shared__ float As[16][68];
    __shared__ float Bs[16][68];
    int tid = threadIdx.x;
    int m0 = blockIdx.x * 64, n0 = blockIdx.y * 64;
    int tm = tid & 15, tn = tid >> 4;
    int lm = tid >> 2, lq = tid & 3;
    float acc[4][4] = {};
    int nkt = (K1 + K2) >> 4;
    for (int kt = 0; kt < nkt; ++kt) {
        int kg = kt << 4;
        const float* A; const float* Bb; int kk; int K;
        if (kg < K1) { A = A1; Bb = B1; kk = kg; K = K1; }
        else         { A = A2; Bb = B2; kk = kg - K1; K = K2; }
        float4 av = *(const float4*)&A[(size_t)(m0 + lm) * K + kk + lq * 4];
        float4 bv = *(const float4*)&Bb[(size_t)(n0 + lm) * K + kk + lq * 4];
        __syncthreads();
        As[lq * 4 + 0][lm] = av.x; As[lq * 4 + 1][lm] = av.y;
        As[lq * 4 + 2][lm] = av.z; As[lq * 4 + 3][lm] = av.w;
        Bs[lq * 4 + 0][lm] = bv.x; Bs[lq * 4 + 1][lm] = bv.y;
        Bs[lq * 4 + 2][lm] = bv.z; Bs[lq * 4 + 3][lm] = bv.w;
        __syncthreads();
#pragma unroll
        for (int k = 0; k < 16; ++k) {
            float4 a = *(const float4*)&As[k][tm * 4];
            float4 b = *(const float4*)&Bs[k][tn * 4];
            acc[0][0] = fmaf(a.x, b.x, acc[0][0]);
            acc[0][1] = fmaf(a.x, b.y, acc[0][1]);
            acc[0][2] = fmaf(a.x, b.z, acc[0][2]);
            acc[0][3] = fmaf(a.x, b.w, acc[0][3]);
            acc[1][0] = fmaf(a.y, b.x, acc[1][0]);
            acc[1][1] = fmaf(a.y, b.y, acc[1][1]);
            acc[1][2] = fmaf(a.y, b.z, acc[1][2]);
            acc[1][3] = fmaf(a.y, b.w, acc[1][3]);
            acc[2][0] = fmaf(a.z, b.x, acc[2][0]);
            acc[2][1] = fmaf(a.z, b.y, acc[2][1]);
            acc[2][2] = fmaf(a.z, b.z, acc[2][2]);
            acc[2][3] = fmaf(a.z, b.w, acc[2][3]);
            acc[3][0] = fmaf(a.w, b.x, acc[3][0]);
            acc[3][1] = fmaf(a.w, b.y, acc[3][1]);
            acc[3][2] = fmaf(a.w, b.z, acc[3][2]);
            acc[3][3] = fmaf(a.w, b.w, acc[3][3]);
        }
    }
    float bb[4] = {0.f, 0.f, 0.f, 0.f};
    if (bias) {
        bb[0] = bias[n0 + tn * 4 + 0]; bb[1] = bias[n0 + tn * 4 + 1];
        bb[2] = bias[n0 + tn * 4 + 2]; bb[3] = bias[n0 + tn * 4 + 3];
    }
#pragma unroll
    for (int i = 0; i < 4; ++i) {
        float4 o = make_float4(acc[i][0] + bb[0], acc[i][1] + bb[1],
                               acc[i][2] + bb[2], acc[i][3] + bb[3]);
        *(float4*)&C[(size_t)(m0 + tm * 4 + i) * N + n0 + tn * 4] = o;
    }
}

// ---------------------------------------------------------------------------
// gru_combine: gate math; write attn_hidden to d_out and X_rnn[:,256:512]
// ---------------------------------------------------------------------------
__global__ __launch_bounds__(256) void gru_combine(
    const float* __restrict__ Cgi, const float* __restrict__ Cgh,
    const float* __restrict__ h_in, float* __restrict__ ah_out,
    float* __restrict__ Xrnn)
{
    int b = blockIdx.x, j = threadIdx.x;
    float gir = Cgi[b * 768 + j], giz = Cgi[b * 768 + 256 + j], gin = Cgi[b * 768 + 512 + j];
    float ghr = Cgh[b * 768 + j], ghz = Cgh[b * 768 + 256 + j], ghn = Cgh[b * 768 + 512 + j];
    float rr = fast_sigmoid(gir + ghr);
    float zz = fast_sigmoid(giz + ghz);
    float nn = fast_tanh(gin + rr * ghn);
    float h = (1.f - zz) * nn + zz * h_in[b * 256 + j];
    ah_out[b * 256 + j] = h;
    Xrnn[b * 832 + 256 + j] = h;
}

// ---------------------------------------------------------------------------
// attn_u: conv1d on (cum,prev) -> loc; u[b,t] = sum_d v[d]*tanh(pq[d]+esp[b,t,d]+pl)
// grid (4 chunks of 150, B). thread d = tid; loc broadcast via v_readlane.
// ---------------------------------------------------------------------------
#define TC 150
__global__ __launch_bounds__(256) void attn_u_kernel(
    const float* __restrict__ esp, const float* __restrict__ pq,
    const float* __restrict__ cum, const float* __restrict__ prv,
    const float* __restrict__ conv_w, const float* __restrict__ L_w,
    const float* __restrict__ L_b, const float* __restrict__ v_w,
    float* __restrict__ u)
{
    __shared__ float loc[TC * 32];
    __shared__ float cw[32 * 2 * 31];
    __shared__ float cumL[TC + 30], prvL[TC + 30];
    __shared__ float upart[4][TC];
    int b = blockIdx.y;
    int t0 = blockIdx.x * TC;
    int tid = threadIdx.x;
    for (int i = tid; i < 32 * 2 * 31; i += 256) cw[i] = conv_w[i];
    for (int i = tid; i < TC + 30; i += 256) {
        int tg = t0 + i - 15;
        bool ok = (tg >= 0) && (tg < T_);
        cumL[i] = ok ? cum[b * T_ + tg] : 0.f;
        prvL[i] = ok ? prv[b * T_ + tg] : 0.f;
    }
    __syncthreads();
    for (int e = tid; e < TC * 32; e += 256) {
        int t = e >> 5, f = e & 31;
        const float* c0 = &cw[f * 62];
        float acc = 0.f;
#pragma unroll
        for (int k = 0; k < 31; ++k)
            acc += cumL[t + k] * c0[k] + prvL[t + k] * c0[31 + k];
        loc[t * 32 + f] = acc;
    }
    int d = tid;
    float rw[32];
    const float4* lw4 = (const float4*)(L_w + d * 32);
#pragma unroll
    for (int q = 0; q < 8; ++q) {
        float4 v = lw4[q];
        rw[4 * q] = v.x; rw[4 * q + 1] = v.y; rw[4 * q + 2] = v.z; rw[4 * q + 3] = v.w;
    }
    float pqv = pq[b * 256 + d] + L_b[d];
    float vd = v_w[d];
    __syncthreads();
    int lane = tid & 63, w = tid >> 6;
    for (int t = 0; t < TC; ++t) {
        float e = esp[((size_t)b * T_ + t0 + t) * 256 + d];
        int locvi = __float_as_int(loc[t * 32 + (tid & 31)]);
        float x = pqv + e;
#pragma unroll
        for (int f = 0; f < 32; ++f)
            x = fmaf(rw[f], __int_as_float(__builtin_amdgcn_readlane(locvi, f)), x);
        float s = fast_tanh(x) * vd;
#pragma unroll
        for (int off = 32; off > 0; off >>= 1) s += __shfl_xor(s, off, 64);
        if (lane == 0) upart[w][t] = s;
    }
    __syncthreads();
    for (int t = tid; t < TC; t += 256)
        u[b * T_ + t0 + t] = upart[0][t] + upart[1][t] + upart[2][t] + upart[3][t];
}

// ---------------------------------------------------------------------------
// softmax + context: scores (d_out), ctx (d_out + X_rnn[:,0:256])
// ---------------------------------------------------------------------------
__global__ __launch_bounds__(1024) void softmax_ctx_kernel(
    const float* __restrict__ u, const int* __restrict__ plen,
    const float* __restrict__ enc,
    float* __restrict__ scores, float* __restrict__ ctx_out,
    float* __restrict__ Xrnn)
{
    __shared__ float sc[T_];
    __shared__ float red[16];
    __shared__ float part[4][256];
    int b = blockIdx.x, tid = threadIdx.x;
    int lane = tid & 63, wid = tid >> 6;
    int pl = plen[b];
    float mv = -1e30f;
    if (tid < T_) {
        float uv = u[b * T_ + tid];
        mv = (tid < pl) ? uv : -1e9f;
        sc[tid] = mv;
    }
    float m = mv;
#pragma unroll
    for (int off = 32; off > 0; off >>= 1) m = fmaxf(m, __shfl_xor(m, off, 64));
    if (lane == 0) red[wid] = m;
    __syncthreads();
    m = red[0];
#pragma unroll
    for (int i = 1; i < 16; ++i) m = fmaxf(m, red[i]);
    float ev = 0.f;
    if (tid < T_) ev = __expf(sc[tid] - m);
    float s = ev;
    __syncthreads();
#pragma unroll
    for (int off = 32; off > 0; off >>= 1) s += __shfl_xor(s, off, 64);
    if (lane == 0) red[wid] = s;
    __syncthreads();
    float tot = 0.f;
#pragma unroll
    for (int i = 0; i < 16; ++i) tot += red[i];
    float inv = __fdividef(1.0f, tot);
    if (tid < T_) {
        float scv = ev * inv;
        scores[b * T_ + tid] = scv;
        sc[tid] = scv;
    }
    __syncthreads();
    int g = tid >> 8, d2 = tid & 255;
    float acc = 0.f;
    for (int t = g; t < T_; t += 4)
        acc = fmaf(sc[t], enc[((size_t)b * T_ + t) * 256 + d2], acc);
    part[g][d2] = acc;
    __syncthreads();
    if (tid < 256) {
        float c = part[0][tid] + part[1][tid] + part[2][tid] + part[3][tid];
        ctx_out[b * 256 + tid] = c;
        Xrnn[b * 832 + tid] = c;
    }
}

// ---------------------------------------------------------------------------
// lstm_combine: gates -> h,c (d_out), x_next = x_in + h (ws)
// ---------------------------------------------------------------------------
__global__ __launch_bounds__(512) void lstm_combine(
    const float* __restrict__ G, const float* __restrict__ bih,
    const float* __restrict__ bhh, const float* __restrict__ c_in,
    const float* __restrict__ x_in, float* __restrict__ h_out,
    float* __restrict__ c_out, float* __restrict__ x_next)
{
    int b = blockIdx.x, j = threadIdx.x;
    size_t base = (size_t)b * 2048;
    float gi = G[base + j] + bih[j] + bhh[j];
    float gf = G[base + 512 + j] + bih[512 + j] + bhh[512 + j];
    float gg = G[base + 1024 + j] + bih[1024 + j] + bhh[1024 + j];
    float go = G[base + 1536 + j] + bih[1536 + j] + bhh[1536 + j];
    float c = fast_sigmoid(gf) * c_in[b * 512 + j] + fast_sigmoid(gi) * fast_tanh(gg);
    float h = fast_sigmoid(go) * fast_tanh(c);
    h_out[b * 512 + j] = h;
    c_out[b * 512 + j] = c;
    x_next[b * 512 + j] = x_in[b * 512 + j] + h;
}

// ---------------------------------------------------------------------------
// mel: mels[b, m, j] = x2[b] . mel_w[m*10+j]  (j < r)
// ---------------------------------------------------------------------------
__global__ __launch_bounds__(256) void mel_kernel(
    const float* __restrict__ x2, const float* __restrict__ mel_w,
    int r, float* __restrict__ mels)
{
    __shared__ float xl[512];
    int b = blockIdx.x, tid = threadIdx.x;
    xl[tid] = x2[b * 512 + tid];
    xl[256 + tid] = x2[b * 512 + 256 + tid];
    __syncthreads();
    for (int idx = tid; idx < 80 * r; idx += 256) {
        int mrow = (idx / r) * 10 + (idx % r);
        const float4* w = (const float4*)(mel_w + (size_t)mrow * 512);
        const float4* xv = (const float4*)xl;
        float acc = 0.f;
#pragma unroll 16
        for (int k = 0; k < 128; ++k) {
            float4 a = w[k], c = xv[k];
            acc += a.x * c.x + a.y * c.y + a.z * c.z + a.w * c.w;
        }
        mels[(size_t)b * 80 * r + idx] = acc;
    }
}

// ---------------------------------------------------------------------------
extern "C" void kernel_launch(void* const* d_in, const int* in_sizes, int n_in,
                              void* d_out, int out_size, void* d_ws, size_t ws_size,
                              hipStream_t stream)
{
    const float* enc    = (const float*)d_in[0];
    const float* esp    = (const float*)d_in[1];
    const float* pre_in = (const float*)d_in[2];
    const float* ah_in  = (const float*)d_in[3];
    const float* h1_in  = (const float*)d_in[4];
    const float* h2_in  = (const float*)d_in[5];
    const float* c1_in  = (const float*)d_in[6];
    const float* c2_in  = (const float*)d_in[7];
    const float* ctx_in = (const float*)d_in[8];
    const float* spk    = (const float*)d_in[9];
    const float* noise  = (const float*)d_in[10];
    const float* cum    = (const float*)d_in[11];
    const float* prv    = (const float*)d_in[12];
    const int*   plen   = (const int*)d_in[13];
    const float* fc1_w  = (const float*)d_in[14];
    const float* fc1_b  = (const float*)d_in[15];
    const float* fc2_w  = (const float*)d_in[16];
    const float* fc2_b  = (const float*)d_in[17];
    const float* conv_w = (const float*)d_in[18];
    const float* L_w    = (const float*)d_in[19];
    const float* L_b    = (const float*)d_in[20];
    const float* W_w    = (const float*)d_in[21];
    const float* W_b    = (const float*)d_in[22];
    const float* v_w    = (const float*)d_in[23];
    const float* g_wih  = (const float*)d_in[24];
    const float* g_whh  = (const float*)d_in[25];
    const float* g_bih  = (const float*)d_in[26];
    const float* g_bhh  = (const float*)d_in[27];
    const float* ri_w   = (const float*)d_in[28];
    const float* ri_b   = (const float*)d_in[29];
    const float* l1_wih = (const float*)d_in[30];
    const float* l1_whh = (const float*)d_in[31];
    const float* l1_bih = (const float*)d_in[32];
    const float* l1_bhh = (const float*)d_in[33];
    const float* l2_wih = (const float*)d_in[34];
    const float* l2_whh = (const float*)d_in[35];
    const float* l2_bih = (const float*)d_in[36];
    const float* l2_bhh = (const float*)d_in[37];
    const float* mel_w  = (const float*)d_in[38];

    // r from host-known out_size: out = 20480*r + 153600 + 65536 + 4*131072 + 65536
    int r = (out_size - 808960) / 20480;
    if (r < 1) r = 1;
    if (r > 10) r = 10;

    float* out    = (float*)d_out;
    float* mels   = out;
    float* scores = out + (size_t)20480 * r;
    float* ah_out = scores + 153600;
    float* h1_out = ah_out + 65536;
    float* h2_out = h1_out + 131072;
    float* c1_out = h2_out + 131072;
    float* c2_out = c1_out + 131072;
    float* ctx_out = c2_out + 131072;

    float* ws   = (float*)d_ws;
    float* Xgru = ws;                    // 256*640   = 163840
    float* Cgi  = Xgru + 163840;         // 256*768   = 196608
    float* Cgh  = Cgi + 196608;          // 196608
    float* pq   = Cgh + 196608;          // 256*256   = 65536
    float* uu   = pq + 65536;            // 256*600   = 153600
    float* Xrnn = uu + 153600;           // 256*832   = 212992
    float* x0   = Xrnn + 212992;         // 256*512   = 131072
    float* x1   = x0 + 131072;           // 131072
    float* x2   = x1 + 131072;           // 131072
    float* G    = x2 + 131072;           // 256*2048  = 524288

    init_concat<<<256, 256, 0, stream>>>(ctx_in, spk, noise, Xgru, Xrnn);
    prenet_kernel<<<256, 256, 0, stream>>>(pre_in, noise, fc1_w, fc1_b, fc2_w, fc2_b, Xgru);
    gemm_dual<<<dim3(4, 12), 256, 0, stream>>>(Xgru, 640, g_wih, nullptr, 0, nullptr, g_bih, Cgi, 768);
    gemm_dual<<<dim3(4, 12), 256, 0, stream>>>(ah_in, 256, g_whh, nullptr, 0, nullptr, g_bhh, Cgh, 768);
    gru_combine<<<256, 256, 0, stream>>>(Cgi, Cgh, ah_in, ah_out, Xrnn);
    gemm_dual<<<dim3(4, 4), 256, 0, stream>>>(ah_out, 256, W_w, nullptr, 0, nullptr, W_b, pq, 256);
    attn_u_kernel<<<dim3(4, 256), 256, 0, stream>>>(esp, pq, cum, prv, conv_w, L_w, L_b, v_w, uu);
    softmax_ctx_kernel<<<256, 1024, 0, stream>>>(uu, plen, enc, scores, ctx_out, Xrnn);
    gemm_dual<<<dim3(4, 8), 256, 0, stream>>>(Xrnn, 832, ri_w, nullptr, 0, nullptr, ri_b, x0, 512);
    gemm_dual<<<dim3(4, 32), 256, 0, stream>>>(x0, 512, l1_wih, h1_in, 512, l1_whh, nullptr, G, 2048);
    lstm_combine<<<256, 512, 0, stream>>>(G, l1_bih, l1_bhh, c1_in, x0, h1_out, c1_out, x1);
    gemm_dual<<<dim3(4, 32), 256, 0, stream>>>(x1, 512, l2_wih, h2_in, 512, l2_whh, nullptr, G, 2048);
    lstm_combine<<<256, 512, 0, stream>>>(G, l2_bih, l2_bhh, c2_in, x1, h2_out, c2_out, x2);
    mel_kernel<<<256, 256, 0, stream>>>(x2, mel_w, r, mels);
}

// Round 2
// 460.271 us; speedup vs baseline: 1.2675x; 1.2675x over previous
//
#include <hip/hip_runtime.h>
#include <hip/hip_bf16.h>
#include <cstdint>

#define B_ 256
#define T_ 600
#define D_ 256

__device__ __forceinline__ float fast_sigmoid(float x) {
    return __fdividef(1.0f, 1.0f + __expf(-x));
}
__device__ __forceinline__ float fast_tanh(float x) {
    return 1.0f - __fdividef(2.0f, __expf(2.0f * x) + 1.0f);
}

// ---------------------------------------------------------------------------
// prenet (+ fused init_concat):
//   Xgru = [ctx_in | prenet_out | spk], Xrnn gets [.., spk, noise]
// ---------------------------------------------------------------------------
__global__ __launch_bounds__(256) void prenet_kernel(
    const float* __restrict__ pre_in, const float* __restrict__ noise,
    const float* __restrict__ w1, const float* __restrict__ b1,
    const float* __restrict__ w2, const float* __restrict__ b2,
    const float* __restrict__ ctx_in, const float* __restrict__ spk,
    float* __restrict__ Xgru, float* __restrict__ Xrnn)
{
    __shared__ float xin[144];
    __shared__ float p1[256];
    int b = blockIdx.x, t = threadIdx.x;
    // init_concat part
    float s = spk[b * 256 + t];
    Xgru[b * 640 + t] = ctx_in[b * 256 + t];
    Xgru[b * 640 + 384 + t] = s;
    Xrnn[b * 832 + 512 + t] = s;
    if (t < 64) Xrnn[b * 832 + 768 + t] = noise[b * 64 + t];
    // prenet
    if (t < 80) xin[t] = pre_in[b * 80 + t];
    else if (t < 144) xin[t] = noise[b * 64 + (t - 80)];
    __syncthreads();
    float acc = b1[t];
    const float4* w = (const float4*)(w1 + t * 144);
    const float4* xi = (const float4*)xin;
#pragma unroll 9
    for (int k = 0; k < 36; ++k) {
        float4 wv = w[k]; float4 xv = xi[k];
        acc += wv.x * xv.x + wv.y * xv.y + wv.z * xv.z + wv.w * xv.w;
    }
    p1[t] = fmaxf(acc, 0.f);
    __syncthreads();
    if (t < 128) {
        float a2 = b2[t];
        const float4* w2v = (const float4*)(w2 + t * 256);
        const float4* pv = (const float4*)p1;
#pragma unroll 8
        for (int k = 0; k < 64; ++k) {
            float4 wv = w2v[k]; float4 xv = pv[k];
            a2 += wv.x * xv.x + wv.y * xv.y + wv.z * xv.z + wv.w * xv.w;
        }
        Xgru[b * 640 + 256 + t] = fmaxf(a2, 0.f);
    }
}

// ---------------------------------------------------------------------------
// gemm_dual: C[M,N] = A1[M,K1] @ B1[N,K1]^T + A2[M,K2] @ B2[N,K2]^T (+bias[n])
// 64x64 tile, 256 threads, 4x4 per thread. M,N multiples of 64; K1,K2 of 16.
// ---------------------------------------------------------------------------
__global__ __launch_bounds__(256) void gemm_dual(
    const float* __restrict__ A1, int K1, const float* __restrict__ B1,
    const float* __restrict__ A2, int K2, const float* __restrict__ B2,
    const float* __restrict__ bias, float* __restrict__ C, int N)
{
    __shared__ float As[16][68];
    __shared__ float Bs[16][68];
    int tid = threadIdx.x;
    int m0 = blockIdx.x * 64, n0 = blockIdx.y * 64;
    int tm = tid & 15, tn = tid >> 4;
    int lm = tid >> 2, lq = tid & 3;
    float acc[4][4] = {};
    int nkt = (K1 + K2) >> 4;
    for (int kt = 0; kt < nkt; ++kt) {
        int kg = kt << 4;
        const float* A; const float* Bb; int kk; int K;
        if (kg < K1) { A = A1; Bb = B1; kk = kg; K = K1; }
        else         { A = A2; Bb = B2; kk = kg - K1; K = K2; }
        float4 av = *(const float4*)&A[(size_t)(m0 + lm) * K + kk + lq * 4];
        float4 bv = *(const float4*)&Bb[(size_t)(n0 + lm) * K + kk + lq * 4];
        __syncthreads();
        As[lq * 4 + 0][lm] = av.x; As[lq * 4 + 1][lm] = av.y;
        As[lq * 4 + 2][lm] = av.z; As[lq * 4 + 3][lm] = av.w;
        Bs[lq * 4 + 0][lm] = bv.x; Bs[lq * 4 + 1][lm] = bv.y;
        Bs[lq * 4 + 2][lm] = bv.z; Bs[lq * 4 + 3][lm] = bv.w;
        __syncthreads();
#pragma unroll
        for (int k = 0; k < 16; ++k) {
            float4 a = *(const float4*)&As[k][tm * 4];
            float4 b = *(const float4*)&Bs[k][tn * 4];
            acc[0][0] = fmaf(a.x, b.x, acc[0][0]);
            acc[0][1] = fmaf(a.x, b.y, acc[0][1]);
            acc[0][2] = fmaf(a.x, b.z, acc[0][2]);
            acc[0][3] = fmaf(a.x, b.w, acc[0][3]);
            acc[1][0] = fmaf(a.y, b.x, acc[1][0]);
            acc[1][1] = fmaf(a.y, b.y, acc[1][1]);
            acc[1][2] = fmaf(a.y, b.z, acc[1][2]);
            acc[1][3] = fmaf(a.y, b.w, acc[1][3]);
            acc[2][0] = fmaf(a.z, b.x, acc[2][0]);
            acc[2][1] = fmaf(a.z, b.y, acc[2][1]);
            acc[2][2] = fmaf(a.z, b.z, acc[2][2]);
            acc[2][3] = fmaf(a.z, b.w, acc[2][3]);
            acc[3][0] = fmaf(a.w, b.x, acc[3][0]);
            acc[3][1] = fmaf(a.w, b.y, acc[3][1]);
            acc[3][2] = fmaf(a.w, b.z, acc[3][2]);
            acc[3][3] = fmaf(a.w, b.w, acc[3][3]);
        }
    }
    float bb[4] = {0.f, 0.f, 0.f, 0.f};
    if (bias) {
        bb[0] = bias[n0 + tn * 4 + 0]; bb[1] = bias[n0 + tn * 4 + 1];
        bb[2] = bias[n0 + tn * 4 + 2]; bb[3] = bias[n0 + tn * 4 + 3];
    }
#pragma unroll
    for (int i = 0; i < 4; ++i) {
        float4 o = make_float4(acc[i][0] + bb[0], acc[i][1] + bb[1],
                               acc[i][2] + bb[2], acc[i][3] + bb[3]);
        *(float4*)&C[(size_t)(m0 + tm * 4 + i) * N + n0 + tn * 4] = o;
    }
}

// ---------------------------------------------------------------------------
// gru_combine
// ---------------------------------------------------------------------------
__global__ __launch_bounds__(256) void gru_combine(
    const float* __restrict__ Cgi, const float* __restrict__ Cgh,
    const float* __restrict__ h_in, float* __restrict__ ah_out,
    float* __restrict__ Xrnn)
{
    int b = blockIdx.x, j = threadIdx.x;
    float gir = Cgi[b * 768 + j], giz = Cgi[b * 768 + 256 + j], gin = Cgi[b * 768 + 512 + j];
    float ghr = Cgh[b * 768 + j], ghz = Cgh[b * 768 + 256 + j], ghn = Cgh[b * 768 + 512 + j];
    float rr = fast_sigmoid(gir + ghr);
    float zz = fast_sigmoid(giz + ghz);
    float nn = fast_tanh(gin + rr * ghn);
    float h = (1.f - zz) * nn + zz * h_in[b * 256 + j];
    ah_out[b * 256 + j] = h;
    Xrnn[b * 832 + 256 + j] = h;
}

// ---------------------------------------------------------------------------
// attn_u v2: 6-way t-batched ILP. grid (4 chunks of 150, B), 256 threads.
// ---------------------------------------------------------------------------
#define TC 150
__global__ __launch_bounds__(256) void attn_u_kernel(
    const float* __restrict__ esp, const float* __restrict__ pq,
    const float* __restrict__ cum, const float* __restrict__ prv,
    const float* __restrict__ conv_w, const float* __restrict__ L_w,
    const float* __restrict__ L_b, const float* __restrict__ v_w,
    float* __restrict__ u)
{
    __shared__ float loc[TC * 32];
    __shared__ float cw[32 * 2 * 31];
    __shared__ float cumL[TC + 30], prvL[TC + 30];
    __shared__ float upart[4][TC];
    int b = blockIdx.y;
    int t0 = blockIdx.x * TC;
    int tid = threadIdx.x;
    for (int i = tid; i < 32 * 2 * 31; i += 256) cw[i] = conv_w[i];
    for (int i = tid; i < TC + 30; i += 256) {
        int tg = t0 + i - 15;
        bool ok = (tg >= 0) && (tg < T_);
        cumL[i] = ok ? cum[b * T_ + tg] : 0.f;
        prvL[i] = ok ? prv[b * T_ + tg] : 0.f;
    }
    __syncthreads();
    for (int e = tid; e < TC * 32; e += 256) {
        int t = e >> 5, f = e & 31;
        const float* c0 = &cw[f * 62];
        float acc = 0.f;
#pragma unroll
        for (int k = 0; k < 31; ++k)
            acc += cumL[t + k] * c0[k] + prvL[t + k] * c0[31 + k];
        loc[t * 32 + f] = acc;
    }
    int d = tid;
    float rw[32];
    const float4* lw4 = (const float4*)(L_w + d * 32);
#pragma unroll
    for (int q = 0; q < 8; ++q) {
        float4 v = lw4[q];
        rw[4 * q] = v.x; rw[4 * q + 1] = v.y; rw[4 * q + 2] = v.z; rw[4 * q + 3] = v.w;
    }
    float pqv = pq[b * 256 + d] + L_b[d];
    float vd = v_w[d];
    __syncthreads();
    int lane = tid & 63, w = tid >> 6;
    int fsel = tid & 31;
    const float* ep = esp + ((size_t)b * T_ + t0) * 256 + d;
    for (int tb = 0; tb < TC; tb += 6) {
        float e0 = ep[0 * 256];
        float e1 = ep[1 * 256];
        float e2 = ep[2 * 256];
        float e3 = ep[3 * 256];
        float e4 = ep[4 * 256];
        float e5 = ep[5 * 256];
        int l0 = __float_as_int(loc[(tb + 0) * 32 + fsel]);
        int l1 = __float_as_int(loc[(tb + 1) * 32 + fsel]);
        int l2 = __float_as_int(loc[(tb + 2) * 32 + fsel]);
        int l3 = __float_as_int(loc[(tb + 3) * 32 + fsel]);
        int l4 = __float_as_int(loc[(tb + 4) * 32 + fsel]);
        int l5 = __float_as_int(loc[(tb + 5) * 32 + fsel]);
        float x0 = pqv + e0, x1 = pqv + e1, x2 = pqv + e2;
        float x3 = pqv + e3, x4 = pqv + e4, x5 = pqv + e5;
#pragma unroll
        for (int f = 0; f < 32; ++f) {
            float wv = rw[f];
            x0 = fmaf(wv, __int_as_float(__builtin_amdgcn_readlane(l0, f)), x0);
            x1 = fmaf(wv, __int_as_float(__builtin_amdgcn_readlane(l1, f)), x1);
            x2 = fmaf(wv, __int_as_float(__builtin_amdgcn_readlane(l2, f)), x2);
            x3 = fmaf(wv, __int_as_float(__builtin_amdgcn_readlane(l3, f)), x3);
            x4 = fmaf(wv, __int_as_float(__builtin_amdgcn_readlane(l4, f)), x4);
            x5 = fmaf(wv, __int_as_float(__builtin_amdgcn_readlane(l5, f)), x5);
        }
        float s0 = fast_tanh(x0) * vd;
        float s1 = fast_tanh(x1) * vd;
        float s2 = fast_tanh(x2) * vd;
        float s3 = fast_tanh(x3) * vd;
        float s4 = fast_tanh(x4) * vd;
        float s5 = fast_tanh(x5) * vd;
#pragma unroll
        for (int off = 32; off > 0; off >>= 1) {
            s0 += __shfl_xor(s0, off, 64);
            s1 += __shfl_xor(s1, off, 64);
            s2 += __shfl_xor(s2, off, 64);
            s3 += __shfl_xor(s3, off, 64);
            s4 += __shfl_xor(s4, off, 64);
            s5 += __shfl_xor(s5, off, 64);
        }
        if (lane == 0) {
            upart[w][tb + 0] = s0;
            upart[w][tb + 1] = s1;
            upart[w][tb + 2] = s2;
            upart[w][tb + 3] = s3;
            upart[w][tb + 4] = s4;
            upart[w][tb + 5] = s5;
        }
        ep += 6 * 256;
    }
    __syncthreads();
    for (int t = tid; t < TC; t += 256)
        u[b * T_ + t0 + t] = upart[0][t] + upart[1][t] + upart[2][t] + upart[3][t];
}

// ---------------------------------------------------------------------------
// softmax + context v2: float4 enc loads, one t-row per wave.
// ---------------------------------------------------------------------------
__global__ __launch_bounds__(1024) void softmax_ctx_kernel(
    const float* __restrict__ u, const int* __restrict__ plen,
    const float* __restrict__ enc,
    float* __restrict__ scores, float* __restrict__ ctx_out,
    float* __restrict__ Xrnn)
{
    __shared__ float sc[T_];
    __shared__ float red[16];
    __shared__ float part[16][256];
    int b = blockIdx.x, tid = threadIdx.x;
    int lane = tid & 63, wid = tid >> 6;
    int pl = plen[b];
    float mv = -1e30f;
    if (tid < T_) {
        float uv = u[b * T_ + tid];
        mv = (tid < pl) ? uv : -1e9f;
        sc[tid] = mv;
    }
    float m = mv;
#pragma unroll
    for (int off = 32; off > 0; off >>= 1) m = fmaxf(m, __shfl_xor(m, off, 64));
    if (lane == 0) red[wid] = m;
    __syncthreads();
    m = red[0];
#pragma unroll
    for (int i = 1; i < 16; ++i) m = fmaxf(m, red[i]);
    float ev = 0.f;
    if (tid < T_) ev = __expf(sc[tid] - m);
    float s = ev;
    __syncthreads();
#pragma unroll
    for (int off = 32; off > 0; off >>= 1) s += __shfl_xor(s, off, 64);
    if (lane == 0) red[wid] = s;
    __syncthreads();
    float tot = 0.f;
#pragma unroll
    for (int i = 0; i < 16; ++i) tot += red[i];
    float inv = __fdividef(1.0f, tot);
    if (tid < T_) {
        float scv = ev * inv;
        scores[b * T_ + tid] = scv;
        sc[tid] = scv;
    }
    __syncthreads();
    // context: wave `wid` handles t = wid, wid+16, ...; lane holds d-quad
    float a0 = 0.f, a1 = 0.f, a2 = 0.f, a3 = 0.f;
    const float4* ep = (const float4*)(enc + ((size_t)b * T_ + wid) * 256) + lane;
    for (int t = wid; t < T_; t += 16) {
        float sv = sc[t];
        float4 ev4 = *ep;
        a0 = fmaf(sv, ev4.x, a0);
        a1 = fmaf(sv, ev4.y, a1);
        a2 = fmaf(sv, ev4.z, a2);
        a3 = fmaf(sv, ev4.w, a3);
        ep += 16 * 64;
    }
    part[wid][lane * 4 + 0] = a0;
    part[wid][lane * 4 + 1] = a1;
    part[wid][lane * 4 + 2] = a2;
    part[wid][lane * 4 + 3] = a3;
    __syncthreads();
    if (tid < 256) {
        float c = 0.f;
#pragma unroll
        for (int q = 0; q < 16; ++q) c += part[q][tid];
        ctx_out[b * 256 + tid] = c;
        Xrnn[b * 832 + tid] = c;
    }
}

// ---------------------------------------------------------------------------
// lstm_combine
// ---------------------------------------------------------------------------
__global__ __launch_bounds__(512) void lstm_combine(
    const float* __restrict__ G, const float* __restrict__ bih,
    const float* __restrict__ bhh, const float* __restrict__ c_in,
    const float* __restrict__ x_in, float* __restrict__ h_out,
    float* __restrict__ c_out, float* __restrict__ x_next)
{
    int b = blockIdx.x, j = threadIdx.x;
    size_t base = (size_t)b * 2048;
    float gi = G[base + j] + bih[j] + bhh[j];
    float gf = G[base + 512 + j] + bih[512 + j] + bhh[512 + j];
    float gg = G[base + 1024 + j] + bih[1024 + j] + bhh[1024 + j];
    float go = G[base + 1536 + j] + bih[1536 + j] + bhh[1536 + j];
    float c = fast_sigmoid(gf) * c_in[b * 512 + j] + fast_sigmoid(gi) * fast_tanh(gg);
    float h = fast_sigmoid(go) * fast_tanh(c);
    h_out[b * 512 + j] = h;
    c_out[b * 512 + j] = c;
    x_next[b * 512 + j] = x_in[b * 512 + j] + h;
}

// ---------------------------------------------------------------------------
// mel
// ---------------------------------------------------------------------------
__global__ __launch_bounds__(256) void mel_kernel(
    const float* __restrict__ x2, const float* __restrict__ mel_w,
    int r, float* __restrict__ mels)
{
    __shared__ float xl[512];
    int b = blockIdx.x, tid = threadIdx.x;
    xl[tid] = x2[b * 512 + tid];
    xl[256 + tid] = x2[b * 512 + 256 + tid];
    __syncthreads();
    for (int idx = tid; idx < 80 * r; idx += 256) {
        int mrow = (idx / r) * 10 + (idx % r);
        const float4* w = (const float4*)(mel_w + (size_t)mrow * 512);
        const float4* xv = (const float4*)xl;
        float acc = 0.f;
#pragma unroll 16
        for (int k = 0; k < 128; ++k) {
            float4 a = w[k], c = xv[k];
            acc += a.x * c.x + a.y * c.y + a.z * c.z + a.w * c.w;
        }
        mels[(size_t)b * 80 * r + idx] = acc;
    }
}

// ---------------------------------------------------------------------------
extern "C" void kernel_launch(void* const* d_in, const int* in_sizes, int n_in,
                              void* d_out, int out_size, void* d_ws, size_t ws_size,
                              hipStream_t stream)
{
    const float* enc    = (const float*)d_in[0];
    const float* esp    = (const float*)d_in[1];
    const float* pre_in = (const float*)d_in[2];
    const float* ah_in  = (const float*)d_in[3];
    const float* h1_in  = (const float*)d_in[4];
    const float* h2_in  = (const float*)d_in[5];
    const float* c1_in  = (const float*)d_in[6];
    const float* c2_in  = (const float*)d_in[7];
    const float* ctx_in = (const float*)d_in[8];
    const float* spk    = (const float*)d_in[9];
    const float* noise  = (const float*)d_in[10];
    const float* cum    = (const float*)d_in[11];
    const float* prv    = (const float*)d_in[12];
    const int*   plen   = (const int*)d_in[13];
    const float* fc1_w  = (const float*)d_in[14];
    const float* fc1_b  = (const float*)d_in[15];
    const float* fc2_w  = (const float*)d_in[16];
    const float* fc2_b  = (const float*)d_in[17];
    const float* conv_w = (const float*)d_in[18];
    const float* L_w    = (const float*)d_in[19];
    const float* L_b    = (const float*)d_in[20];
    const float* W_w    = (const float*)d_in[21];
    const float* W_b    = (const float*)d_in[22];
    const float* v_w    = (const float*)d_in[23];
    const float* g_wih  = (const float*)d_in[24];
    const float* g_whh  = (const float*)d_in[25];
    const float* g_bih  = (const float*)d_in[26];
    const float* g_bhh  = (const float*)d_in[27];
    const float* ri_w   = (const float*)d_in[28];
    const float* ri_b   = (const float*)d_in[29];
    const float* l1_wih = (const float*)d_in[30];
    const float* l1_whh = (const float*)d_in[31];
    const float* l1_bih = (const float*)d_in[32];
    const float* l1_bhh = (const float*)d_in[33];
    const float* l2_wih = (const float*)d_in[34];
    const float* l2_whh = (const float*)d_in[35];
    const float* l2_bih = (const float*)d_in[36];
    const float* l2_bhh = (const float*)d_in[37];
    const float* mel_w  = (const float*)d_in[38];

    int r = (out_size - 808960) / 20480;
    if (r < 1) r = 1;
    if (r > 10) r = 10;

    float* out    = (float*)d_out;
    float* mels   = out;
    float* scores = out + (size_t)20480 * r;
    float* ah_out = scores + 153600;
    float* h1_out = ah_out + 65536;
    float* h2_out = h1_out + 131072;
    float* c1_out = h2_out + 131072;
    float* c2_out = c1_out + 131072;
    float* ctx_out = c2_out + 131072;

    float* ws   = (float*)d_ws;
    float* Xgru = ws;                    // 256*640
    float* Cgi  = Xgru + 163840;         // 256*768
    float* Cgh  = Cgi + 196608;
    float* pq   = Cgh + 196608;          // 256*256
    float* uu   = pq + 65536;            // 256*600
    float* Xrnn = uu + 153600;           // 256*832
    float* x0   = Xrnn + 212992;         // 256*512
    float* x1   = x0 + 131072;
    float* x2   = x1 + 131072;
    float* G    = x2 + 131072;           // 256*2048

    prenet_kernel<<<256, 256, 0, stream>>>(pre_in, noise, fc1_w, fc1_b, fc2_w, fc2_b,
                                           ctx_in, spk, Xgru, Xrnn);
    gemm_dual<<<dim3(4, 12), 256, 0, stream>>>(Xgru, 640, g_wih, nullptr, 0, nullptr, g_bih, Cgi, 768);
    gemm_dual<<<dim3(4, 12), 256, 0, stream>>>(ah_in, 256, g_whh, nullptr, 0, nullptr, g_bhh, Cgh, 768);
    gru_combine<<<256, 256, 0, stream>>>(Cgi, Cgh, ah_in, ah_out, Xrnn);
    gemm_dual<<<dim3(4, 4), 256, 0, stream>>>(ah_out, 256, W_w, nullptr, 0, nullptr, W_b, pq, 256);
    attn_u_kernel<<<dim3(4, 256), 256, 0, stream>>>(esp, pq, cum, prv, conv_w, L_w, L_b, v_w, uu);
    softmax_ctx_kernel<<<256, 1024, 0, stream>>>(uu, plen, enc, scores, ctx_out, Xrnn);
    gemm_dual<<<dim3(4, 8), 256, 0, stream>>>(Xrnn, 832, ri_w, nullptr, 0, nullptr, ri_b, x0, 512);
    gemm_dual<<<dim3(4, 32), 256, 0, stream>>>(x0, 512, l1_wih, h1_in, 512, l1_whh, nullptr, G, 2048);
    lstm_combine<<<256, 512, 0, stream>>>(G, l1_bih, l1_bhh, c1_in, x0, h1_out, c1_out, x1);
    gemm_dual<<<dim3(4, 32), 256, 0, stream>>>(x1, 512, l2_wih, h2_in, 512, l2_whh, nullptr, G, 2048);
    lstm_combine<<<256, 512, 0, stream>>>(G, l2_bih, l2_bhh, c2_in, x1, h2_out, c2_out, x2);
    mel_kernel<<<256, 256, 0, stream>>>(x2, mel_w, r, mels);
}